// Round 11
// baseline (86.850 us; speedup 1.0000x reference)
//
#include <hip/hip_runtime.h>
#include <math.h>

#define NSHOT 5
#define WAY 32
#define DIM 640
#define NQ 4096
#define RNEAR 10

// ---- workspace layout (float offsets) — R6-proven footprint ----
constexpr int OFF_PROTOS = 0;        // 32*640
constexpr int OFF_QPART  = 20480;    // 128*640 column partial sums (incl. shot fold)
constexpr int OFF_C      = 102400;   // 32
constexpr int OFF_XVEC   = 102432;   // 32*640 (proto_p)
constexpr int OFF_DIS    = 122912;   // 32*4096
constexpr int OFF_S      = 253984;   // 32
constexpr int OFF_U      = 254016;   // 32
constexpr int OFF_NID    = 254048;   // 32*10
constexpr int OFF_TP     = 254368;   // 32*640 (test_proto)
constexpr int OFF_NIDX   = 274848;   // 32*10 ints
constexpr int OFF_Q2D    = 275200;   // double[4096]
constexpr int OFF_X2D    = 283392;   // double[32] (proto_p norms^2)
constexpr int OFF_X2D2   = 283456;   // double[32] (test_proto norms^2)

__device__ __forceinline__ double wave_sum_d(double v) {
#pragma unroll
  for (int o = 32; o > 0; o >>= 1) v += __shfl_down(v, o, 64);
  return v;
}

__device__ __forceinline__ double dist_hyp(double c, double xdotq, double u2, double q2) {
  const double EPSd = 1e-5;
  double sc = sqrt(c);
  double nq = sqrt(q2);
  double nf = fmax(nq, EPSd);
  double th = tanh(sc * nf);
  double al = th / (sc * nf);
  double ny = fmax(al * nq, EPSd);
  double mx = 0.999 / sc;
  if (ny > mx) al *= mx / ny;
  double y2 = al * al * q2;
  double uy = -al * xdotq;
  double A = 1.0 + 2.0 * c * uy + c * y2;
  double B = 1.0 - c * u2;
  double den = fmax(1.0 + 2.0 * c * uy + c * c * u2 * y2, EPSd);
  double num2 = fmax(A * A * u2 + 2.0 * A * B * uy + B * B * y2, 0.0);
  double n = sqrt(num2) / den;
  double arg = sc * n;
  const double CLIP = (double)(1.0f - 1e-5f);
  arg = fmin(fmax(arg, 0.0), CLIP);
  return (1.0 / sc) * log((1.0 + arg) / (1.0 - arg));
}

__device__ __forceinline__ double expmap_scale(double c, double p2, double* u2out) {
  double sc = sqrt(c);
  double ntrue = sqrt(p2);
  double nf = fmax(ntrue, 1e-5);
  double th = tanh(sc * nf);
  double s0 = th / (sc * nf);
  double ny = fmax(s0 * ntrue, 1e-5);
  double mx = 0.999 / sc;
  if (ny > mx) s0 *= mx / ny;
  *u2out = s0 * s0 * p2;
  return s0;
}

// grid 128 x 640thr: protos (b<32), per-row q2 (f64), QPART rows (Q cols + shot fold)
__global__ __launch_bounds__(640) void k_fuse1(const float* __restrict__ Qm,
                                               const float* __restrict__ shot, float* ws) {
  __shared__ double q2w[32][10];
  int b = blockIdx.x, t = threadIdx.x;
  int lane = t & 63, wid = t >> 6;  // 10 waves
  float protoval = 0.f;
  if (b < WAY) {
    float s = 0.f;
#pragma unroll
    for (int s5 = 0; s5 < NSHOT; ++s5) s += shot[(size_t)(s5 * WAY + b) * DIM + t];
    protoval = s * 0.2f;
    ws[OFF_PROTOS + b * DIM + t] = protoval;
  }
  int r0 = b * 32;
  float colacc = 0.f;
  for (int r = 0; r < 32; ++r) {
    float v = Qm[(size_t)(r0 + r) * DIM + t];
    colacc += v;
    double sq = (double)v * v;
    sq = wave_sum_d(sq);
    if (lane == 0) q2w[r][wid] = sq;
  }
  ws[OFF_QPART + b * DIM + t] = colacc + 5.f * protoval;  // shot contribution folded in
  __syncthreads();
  if (t < 32) {
    double s = 0.0;
#pragma unroll
    for (int k = 0; k < 10; ++k) s += q2w[t][k];
    ((double*)(ws + OFF_Q2D))[r0 + t] = s;
  }
}

// controller MLP, 512 threads: parallel float4 am-reduction + float4 W1 GEMM
__global__ __launch_bounds__(512) void k_ctrl(const float* __restrict__ W1, const float* __restrict__ b1,
                                              const float* __restrict__ W2, const float* __restrict__ b2,
                                              const float* __restrict__ W3, const float* __restrict__ b3,
                                              float* ws) {
  __shared__ float cat[2 * DIM];           // [pr | am]
  __shared__ float4 ampart[3][160];
  __shared__ float h1p[16][128];
  __shared__ float h1s[128];
  __shared__ float h2p[8][64], h2s[64];
  __shared__ float lg[5];
  __shared__ double redd[8];
  __shared__ double sBeta;
  int w = blockIdx.x, t = threadIdx.x;
  int lane = t & 63, wid = t >> 6;   // 8 waves
  double ps = 0.0;
  for (int d = t; d < DIM; d += 512) {
    float v = ws[OFF_PROTOS + w * DIM + d];
    cat[d] = v; ps += (double)v * v;
  }
  ps = wave_sum_d(ps);
  if (lane == 0) redd[wid] = ps;
  if (t < 480) {
    int s = t / 160, quad = t - s * 160;
    int p0 = s * 43, p1 = (s == 2) ? 128 : (p0 + 43);
    float4 a = {0.f, 0.f, 0.f, 0.f};
#pragma unroll 4
    for (int p = p0; p < p1; ++p) {
      float4 v = *(const float4*)&ws[OFF_QPART + p * DIM + quad * 4];
      a.x += v.x; a.y += v.y; a.z += v.z; a.w += v.w;
    }
    ampart[s][quad] = a;
  }
  __syncthreads();
  if (t < 160) {
    float4 a = ampart[0][t], b4 = ampart[1][t], c4 = ampart[2][t];
    float4 r;
    r.x = (a.x + b4.x + c4.x) / 4256.f;
    r.y = (a.y + b4.y + c4.y) / 4256.f;
    r.z = (a.z + b4.z + c4.z) / 4256.f;
    r.w = (a.w + b4.w + c4.w) / 4256.f;
    *(float4*)&cat[DIM + t * 4] = r;
  }
  __syncthreads();
  {
    int ng = t & 31, ks = t >> 5;
    int k0 = ks * 80;
    float4 acc = {0.f, 0.f, 0.f, 0.f};
#pragma unroll 8
    for (int k = k0; k < k0 + 80; ++k) {
      float4 wr = *(const float4*)&W1[(size_t)k * 128 + ng * 4];
      float xv = cat[k];
      acc.x = fmaf(xv, wr.x, acc.x);
      acc.y = fmaf(xv, wr.y, acc.y);
      acc.z = fmaf(xv, wr.z, acc.z);
      acc.w = fmaf(xv, wr.w, acc.w);
    }
    *(float4*)&h1p[ks][ng * 4] = acc;
  }
  __syncthreads();
  if (t < 128) {
    float a = b1[t];
#pragma unroll
    for (int s = 0; s < 16; ++s) a += h1p[s][t];
    h1s[t] = fmaxf(a, 0.f);
  }
  __syncthreads();
  {
    int n = t & 63, s2 = t >> 6;
    int k0 = s2 * 16;
    float acc = 0.f;
#pragma unroll
    for (int k = 0; k < 16; ++k) acc = fmaf(h1s[k0 + k], W2[(size_t)(k0 + k) * 64 + n], acc);
    h2p[s2][n] = acc;
  }
  __syncthreads();
  if (t < 64) {
    float a = b2[t];
#pragma unroll
    for (int s = 0; s < 8; ++s) a += h2p[s][t];
    h2s[t] = fmaxf(a, 0.f);
  }
  __syncthreads();
  if (t < 5) {
    float a = b3[t];
    for (int k = 0; k < 64; ++k) a = fmaf(h2s[k], W3[k * 5 + t], a);
    lg[t] = a;
  }
  __syncthreads();
  if (t == 0) {
    double p2 = 0.0;
    for (int i = 0; i < 8; ++i) p2 += redd[i];
    double m = lg[0];
    for (int i = 1; i < 5; ++i) m = fmax(m, (double)lg[i]);
    double se = 0.0, cv = 0.0;
    for (int i = 0; i < 5; ++i) { double e = exp((double)lg[i] - m); se += e; cv += e * 0.2 * (double)(i + 1); }
    double c = cv / se;
    ws[OFF_C + w] = (float)c;
    double u2;
    sBeta = expmap_scale(c, p2, &u2);
    ((double*)(ws + OFF_X2D))[w] = u2;
  }
  __syncthreads();
  float beta = (float)sBeta;
  for (int d = t; d < DIM; d += 512) ws[OFF_XVEC + w * DIM + d] = beta * cat[d];
}

// full-K GEMM: grid 512 (8q each) x 256 thr, one output/thread (q=t&7, w=t>>3).
// Single barrier per K-chunk double-buffer step.
__global__ __launch_bounds__(256) void k_gemmdist(const float* __restrict__ X, const float* __restrict__ Qm,
                                                  float* __restrict__ ws, int mode, float* __restrict__ out) {
  __shared__ float S[2][40][68];   // rows 0..7 = Q, rows 8..39 = X
  int t = threadIdx.x;
  int q0 = blockIdx.x * 8;
  int rowA = t >> 4, quadA = t & 15;
  int rowB = (t + 256) >> 4;          // 16..31 -> X rows 8..23
  int rowC = (t + 512) >> 4;          // 32..39 -> X rows 24..31
  bool hasC = (t < 128);
  const float* srcA = (rowA < 8 ? Qm + (size_t)(q0 + rowA) * DIM : X + (size_t)(rowA - 8) * DIM) + quadA * 4;
  const float* srcB = X + (size_t)(rowB - 8) * DIM + quadA * 4;
  const float* srcC = X + (size_t)(rowC - 8) * DIM + quadA * 4;
  float4 pA = *(const float4*)srcA;
  float4 pB = *(const float4*)srcB;
  float4 pC = {0.f, 0.f, 0.f, 0.f};
  if (hasC) pC = *(const float4*)srcC;
  *(float4*)&S[0][rowA][quadA * 4] = pA;
  *(float4*)&S[0][rowB][quadA * 4] = pB;
  if (hasC) *(float4*)&S[0][rowC][quadA * 4] = pC;
  __syncthreads();
  int q = t & 7, w = t >> 3;
  float ax = 0.f, ay = 0.f, az = 0.f, aw = 0.f;
  for (int c = 0; c < 10; ++c) {
    int bsel = c & 1;
    if (c < 9) {
      size_t kc = (size_t)(c + 1) * 64;
      pA = *(const float4*)(srcA + kc);
      pB = *(const float4*)(srcB + kc);
      if (hasC) pC = *(const float4*)(srcC + kc);
    }
    const float* qr = &S[bsel][q][0];
    const float* xr = &S[bsel][8 + w][0];
#pragma unroll
    for (int kk = 0; kk < 64; kk += 4) {
      float4 qv = *(const float4*)(qr + kk);
      float4 xv = *(const float4*)(xr + kk);
      ax = fmaf(qv.x, xv.x, ax);
      ay = fmaf(qv.y, xv.y, ay);
      az = fmaf(qv.z, xv.z, az);
      aw = fmaf(qv.w, xv.w, aw);
    }
    if (c < 9) {
      // write the buffer nobody reads this iteration; barrier ends the step.
      int nb = bsel ^ 1;
      *(float4*)&S[nb][rowA][quadA * 4] = pA;
      *(float4*)&S[nb][rowB][quadA * 4] = pB;
      if (hasC) *(float4*)&S[nb][rowC][quadA * 4] = pC;
      __syncthreads();
    }
  }
  float acc = (ax + ay) + (az + aw);
  const double* q2d   = (const double*)(ws + OFF_Q2D);
  const double* u2arr = (const double*)(ws + (mode ? OFF_X2D2 : OFF_X2D));
  int qq = q0 + q;
  double d = dist_hyp((double)ws[OFF_C + w], (double)acc, u2arr[w], q2d[qq]);
  if (mode == 0) {
    ws[OFF_DIS + (size_t)w * NQ + qq] = (float)d;
  } else {
    out[(size_t)qq * WAY + w] = (float)(-d / 16.0);
  }
}

// per-way: row sum S, first-10 col sum U, stable top-10.
// Stage 1: per-wave top-10 via shfl_xor butterflies (no barriers).
// Stage 2: one wave merges 16x10 candidates. One block barrier total.
__global__ __launch_bounds__(1024) void k_topk(float* ws, int* nidx) {
  __shared__ double sredS[16], sredU[16];
  __shared__ float cval[160];
  __shared__ int cidx[160];
  int w = blockIdx.x, t = threadIdx.x;
  int lane = t & 63, wid = t >> 6;   // 16 waves
  const float* base = ws + OFF_DIS + (size_t)w * NQ;
  float v0 = base[t], v1 = base[1024 + t], v2 = base[2048 + t], v3 = base[3072 + t];
  unsigned tk = 0;
  double s = (double)v0 + (double)v1 + (double)v2 + (double)v3;
  double u = (t < RNEAR) ? (double)v0 : 0.0;
  s = wave_sum_d(s);
  u = wave_sum_d(u);
  if (lane == 0) { sredS[wid] = s; sredU[wid] = u; }
  // stage 1: this wave's top-10 over its 256 values
  for (int r = 0; r < RNEAR; ++r) {
    float lv = INFINITY; int li = 0x7fffffff;
    if (!(tk & 1u) && (v0 < lv || (v0 == lv && t < li)))        { lv = v0; li = t; }
    if (!(tk & 2u) && (v1 < lv || (v1 == lv && 1024 + t < li))) { lv = v1; li = 1024 + t; }
    if (!(tk & 4u) && (v2 < lv || (v2 == lv && 2048 + t < li))) { lv = v2; li = 2048 + t; }
    if (!(tk & 8u) && (v3 < lv || (v3 == lv && 3072 + t < li))) { lv = v3; li = 3072 + t; }
#pragma unroll
    for (int o = 32; o > 0; o >>= 1) {
      float ov = __shfl_xor(lv, o, 64);
      int oi = __shfl_xor(li, o, 64);
      if (ov < lv || (ov == lv && oi < li)) { lv = ov; li = oi; }
    }
    // all lanes hold the wave winner now
    if (lane == 0) { cval[wid * RNEAR + r] = lv; cidx[wid * RNEAR + r] = li; }
    if ((li & 1023) == t) tk |= 1u << (li >> 10);   // owning lane marks taken
  }
  __syncthreads();
  if (t == 0) {
    double S = 0.0, U = 0.0;
    for (int k = 0; k < 16; ++k) { S += sredS[k]; U += sredU[k]; }
    ws[OFF_S + w] = (float)S;
    ws[OFF_U + w] = (float)U;
  }
  if (t < 64) {
    // wave 0 merges 160 candidates: lane holds slots t, t+64, t+128(<32)
    float c0 = cval[t], c1 = cval[t + 64];
    int i0 = cidx[t], i1 = cidx[t + 64];
    float c2 = (t < 32) ? cval[t + 128] : INFINITY;
    int i2 = (t < 32) ? cidx[t + 128] : 0x7fffffff;
    unsigned m = 0;
    for (int r = 0; r < RNEAR; ++r) {
      float lv = INFINITY; int li = 0x7fffffff;
      if (!(m & 1u) && (c0 < lv || (c0 == lv && i0 < li))) { lv = c0; li = i0; }
      if (!(m & 2u) && (c1 < lv || (c1 == lv && i1 < li))) { lv = c1; li = i1; }
      if (!(m & 4u) && (c2 < lv || (c2 == lv && i2 < li))) { lv = c2; li = i2; }
#pragma unroll
      for (int o = 32; o > 0; o >>= 1) {
        float ov = __shfl_xor(lv, o, 64);
        int oi = __shfl_xor(li, o, 64);
        if (ov < lv || (ov == lv && oi < li)) { lv = ov; li = oi; }
      }
      if (lane == 0) {
        ws[OFF_NID + w * RNEAR + r] = lv;
        nidx[w * RNEAR + r] = li;
      }
      // global q-index is unique across candidates -> safe taken-marking
      if (i0 == li) m |= 1u;
      if (i1 == li) m |= 2u;
      if (i2 == li) m |= 4u;
    }
  }
}

// fused: per-way stats + refine MLP + tmp/expmap -> TP
__global__ __launch_bounds__(512) void k_reftmp(const float* __restrict__ Qm,
                                                const float* __restrict__ Wr1, const float* __restrict__ br1,
                                                const float* __restrict__ Wr2, const float* __restrict__ br2,
                                                float* ws, const int* __restrict__ nidx) {
  __shared__ float colsh[RNEAR][33];
  __shared__ float rr[22];
  __shared__ float qjNid[RNEAR];
  __shared__ int qj[RNEAR];
  __shared__ float Ssh[WAY], Ush[WAY];
  __shared__ float hr[RNEAR], iw[RNEAR];
  __shared__ float onw_sh;
  __shared__ double p2red[8];
  __shared__ double gshd;
  int w = blockIdx.x, t = threadIdx.x;
  int lane = t & 63, wid = t >> 6;
  if (t < WAY) { Ssh[t] = ws[OFF_S + t]; Ush[t] = ws[OFF_U + t]; }
  if (t >= 64 && t < 64 + RNEAR) {
    int j = t - 64;
    qj[j] = nidx[w * RNEAR + j];
    qjNid[j] = ws[OFF_NID + w * RNEAR + j];
  }
  __syncthreads();
  if (t < WAY * RNEAR) {
    int j = t >> 5, w2 = t & 31;
    colsh[j][w2] = ws[OFF_DIS + (size_t)w2 * NQ + qj[j]];
  }
  __syncthreads();
  if (t < RNEAR) {
    double cs = 0.0, pc = 0.0;
    for (int w2 = 0; w2 < WAY; ++w2) {
      float dv = colsh[t][w2];
      cs += dv;
      if (w2 < w) pc += dv;
    }
    rr[t] = qjNid[t];
    rr[RNEAR + t] = (float)((cs - qjNid[t]) / (double)(WAY - 1));
    colsh[t][32] = (float)pc;
  }
  __syncthreads();
  if (t == 0) {
    double sn = 0.0; for (int j = 0; j < RNEAR; ++j) sn += rr[j];
    double oi = ((double)Ssh[w] - sn) / (double)(NQ - RNEAR);
    double pref = 0.0; for (int j = 0; j < w; ++j) pref += Ssh[j];
    double suf = 0.0; for (int j = w + 1; j < WAY; ++j) suf += (double)Ssh[j] - (double)Ush[j];
    double spc = 0.0; for (int j = 0; j < RNEAR; ++j) spc += colsh[j][32];
    rr[20] = (float)oi;
    rr[21] = (float)((pref - spc + suf) / ((double)(WAY - 1) * (double)(NQ - RNEAR)));
  }
  __syncthreads();
  if (t < RNEAR) {
    float a = br1[t];
    for (int k = 0; k < 22; ++k) a = fmaf(rr[k], Wr1[k * RNEAR + t], a);
    hr[t] = fmaxf(a, 0.f);
  }
  __syncthreads();
  if (t == 0) {
    double o[11];
    for (int r2 = 0; r2 < 11; ++r2) {
      float a = br2[r2];
      for (int k = 0; k < RNEAR; ++k) a = fmaf(hr[k], Wr2[k * 11 + r2], a);
      o[r2] = a;
    }
    double m = o[0]; for (int i = 1; i < RNEAR; ++i) m = fmax(m, o[i]);
    double se = 0.0; double e[RNEAR];
    for (int i = 0; i < RNEAR; ++i) { e[i] = exp(o[i] - m); se += e[i]; }
    for (int i = 0; i < RNEAR; ++i) iw[i] = (float)(e[i] / se);
    onw_sh = (float)(1.0 / (1.0 + exp(-o[10])));
  }
  __syncthreads();
  float onwv = onw_sh;
  float a0 = 0.f, a1 = 0.f;
  bool has2 = (t + 512 < DIM);
  double ls = 0.0;
  {
    int d = t;
    float wd = 0.f;
#pragma unroll
    for (int j = 0; j < RNEAR; ++j) wd = fmaf(Qm[(size_t)qj[j] * DIM + d], iw[j], wd);
    a0 = ws[OFF_PROTOS + w * DIM + d] * onwv + wd * (1.f - onwv);
    ls += (double)a0 * a0;
  }
  if (has2) {
    int d = t + 512;
    float wd = 0.f;
#pragma unroll
    for (int j = 0; j < RNEAR; ++j) wd = fmaf(Qm[(size_t)qj[j] * DIM + d], iw[j], wd);
    a1 = ws[OFF_PROTOS + w * DIM + d] * onwv + wd * (1.f - onwv);
    ls += (double)a1 * a1;
  }
  ls = wave_sum_d(ls);
  if (lane == 0) p2red[wid] = ls;
  __syncthreads();
  if (t == 0) {
    double p2 = 0.0;
    for (int i = 0; i < 8; ++i) p2 += p2red[i];
    double c = (double)ws[OFF_C + w];
    double u2;
    gshd = expmap_scale(c, p2, &u2);
    ((double*)(ws + OFF_X2D2))[w] = u2;
  }
  __syncthreads();
  float g = (float)gshd;
  ws[OFF_TP + w * DIM + t] = g * a0;
  if (has2) ws[OFF_TP + w * DIM + t + 512] = g * a1;
}

extern "C" void kernel_launch(void* const* d_in, const int* in_sizes, int n_in,
                              void* d_out, int out_size, void* d_ws, size_t ws_size,
                              hipStream_t stream) {
  (void)in_sizes; (void)n_in; (void)out_size; (void)ws_size;
  const float* shot = (const float*)d_in[0];
  const float* qry  = (const float*)d_in[1];
  const float* W1   = (const float*)d_in[2];
  const float* b1   = (const float*)d_in[3];
  const float* W2   = (const float*)d_in[4];
  const float* b2   = (const float*)d_in[5];
  const float* W3   = (const float*)d_in[6];
  const float* b3   = (const float*)d_in[7];
  const float* Wr1  = (const float*)d_in[8];
  const float* br1  = (const float*)d_in[9];
  const float* Wr2  = (const float*)d_in[10];
  const float* br2  = (const float*)d_in[11];
  float* ws = (float*)d_ws;
  float* out = (float*)d_out;
  int* nidx = (int*)(ws + OFF_NIDX);

  hipLaunchKernelGGL(k_fuse1,    dim3(128), dim3(640), 0, stream, qry, shot, ws);
  hipLaunchKernelGGL(k_ctrl,     dim3(32), dim3(512), 0, stream, W1, b1, W2, b2, W3, b3, ws);
  hipLaunchKernelGGL(k_gemmdist, dim3(512), dim3(256), 0, stream, ws + OFF_XVEC, qry, ws, 0, out);
  hipLaunchKernelGGL(k_topk,     dim3(32), dim3(1024), 0, stream, ws, nidx);
  hipLaunchKernelGGL(k_reftmp,   dim3(32), dim3(512), 0, stream, qry, Wr1, br1, Wr2, br2, ws, nidx);
  hipLaunchKernelGGL(k_gemmdist, dim3(512), dim3(256), 0, stream, ws + OFF_TP, qry, ws, 1, out);
}